// Round 1
// 103.097 us; speedup vs baseline: 1.0280x; 1.0280x over previous
//
#include <hip/hip_runtime.h>
#include <hip/hip_bf16.h>

// QKVAttentionLegacy: qkv (4,3072,1024) fp32, 16 heads, ch=64.
// R9 = R8 + (a) 512-thread blocks: 8 waves/block, 16 t-rows/wave, 2 blocks/CU
//      -> 16 waves/CU (4/SIMD, 50% occupancy cap, was 25%); K staged by waves
//      0-3, V by waves 4-7 (wave-uniform split, halves per-wave staging).
//      (b) in-register P: S^T C-layout -> PV B-frag via v_cvt_pk_bf16_f32 +
//      v_permlane32_swap_b32 + v_permlane16_swap_b32 (no LDS round-trip for P).
//      Derivation: af[kk] dword d at lane(q,t) = pack(P[t][32kk+8q+2d],[+1]);
//      St[sb][r] at lane(qs,t) = P[t][16sb+4qs+r]. With X=c01[2kk],Y=c01[2kk+1]:
//      swap32(X,Y) -> X'={X.r0,X.r1,Y.r0,Y.r1}, Y'={X.r2,X.r3,Y.r2,Y.r3};
//      swap16(X',Y') -> X''={X.r0,X.r2,Y.r0,Y.r2}=d0, Y''={X.r1,X.r3,Y.r1,Y.r3}=d2.
//      c23 pair gives d1,d3. K/V/Q LDS swizzles identical to R8 (verified floors).
// PV stays one tile behind (fills exp2 latency); V triple-buffered, K double,
// ONE barrier/iter (last skipped).

typedef __bf16 bf16_8 __attribute__((ext_vector_type(8)));
typedef __bf16 bf16_4 __attribute__((ext_vector_type(4)));
typedef float floatx4 __attribute__((ext_vector_type(4)));

#define NTHREADS 512
#define STR 64               // bf16 elems per LDS row (128 B, swizzle not pad)
#define NSTEPS 16

#if __has_builtin(__builtin_amdgcn_exp2f)
#define EXP2(x) __builtin_amdgcn_exp2f(x)
#else
#define EXP2(x) exp2f(x)
#endif
// (1/8)*log2(e): qk scale + exp->exp2, folded into Q staging (one bf16 rounding).
#define QSCALE 0.18033688011112042f

// LDS: q_s [128][64]bf16 @0 (16384, dead after qf loads)
//      k0 @16384 | k1 @24576 | v0 @32768 | v1 @40960 | v2 @49152 (each 8192)
#define LDS_BYTES 57344

__device__ __forceinline__ int kap(int row) { return ((row >> 1) + (row >> 4)) & 7; }

__device__ __forceinline__ unsigned pk_bf16(float a, float b) {
    unsigned r;
    asm("v_cvt_pk_bf16_f32 %0, %1, %2" : "=v"(r) : "v"(a), "v"(b));
    return r;
}
// vdst rows{2,3} <-> vsrc rows{0,1} (16-lane rows)
__device__ __forceinline__ void swap32(unsigned& x, unsigned& y) {
    asm("v_permlane32_swap_b32 %0, %1" : "+v"(x), "+v"(y));
}
// vdst rows{1,3} <-> vsrc rows{0,2}
__device__ __forceinline__ void swap16(unsigned& x, unsigned& y) {
    asm("v_permlane16_swap_b32 %0, %1" : "+v"(x), "+v"(y));
}

__device__ __forceinline__ void write_k(__bf16* kn, const float4* r, int si, int sG) {
    #pragma unroll
    for (int rr = 0; rr < 4; ++rr) {
        int srow = si * 4 + rr;
        bf16_4 w;
        w[0] = (__bf16)((const float*)&r[0])[rr];
        w[1] = (__bf16)((const float*)&r[1])[rr];
        w[2] = (__bf16)((const float*)&r[2])[rr];
        w[3] = (__bf16)((const float*)&r[3])[rr];
        *(bf16_4*)&kn[srow * STR + ((sG ^ (kap(srow) << 1)) << 2)] = w;
    }
}
__device__ __forceinline__ void write_v(__bf16* vn, const float4* r, int si, int c0) {
    #pragma unroll
    for (int jj = 0; jj < 4; ++jj) {
        int c = c0 + jj;
        bf16_4 w;
        w[0] = (__bf16)r[jj].x; w[1] = (__bf16)r[jj].y;
        w[2] = (__bf16)r[jj].z; w[3] = (__bf16)r[jj].w;
        *(bf16_4*)&vn[c * STR + ((si ^ (kap(c) << 1)) << 2)] = w;
    }
}

__global__ __launch_bounds__(NTHREADS, 4)
void attn_kernel(const float* __restrict__ qkv, float* __restrict__ out) {
    __shared__ char smem[LDS_BYTES];
    __bf16* q_s = (__bf16*)smem;
    __bf16* k0  = (__bf16*)(smem + 16384);
    __bf16* k1  = (__bf16*)(smem + 24576);
    __bf16* v0  = (__bf16*)(smem + 32768);
    __bf16* v1  = (__bf16*)(smem + 40960);
    __bf16* v2  = (__bf16*)(smem + 49152);

    const int tid  = threadIdx.x;
    const int wave = tid >> 6;           // 0..7, owns t-rows [16w, 16w+16)
    const int lane = tid & 63;
    const int quad = lane >> 4;
    const int i16  = lane & 15;

    const int bx = blockIdx.x;           // 512 = 8 t-tiles * 64 bh (bh fastest -> XCD)
    const int bh = bx & 63;
    const int t0 = (bx >> 6) << 7;       // *128

    const float* qg = qkv + (size_t)bh * 196608;
    const float* kg = qg + 65536;
    const float* vg = qg + 131072;

    // staging split: waves 0-3 stage K, waves 4-7 stage V (wave-uniform)
    const int sv = tid >> 8;             // 0 = K-stager, 1 = V-stager
    const int st = tid & 255;
    const int si = st & 15;
    const int sG = st >> 4;              // c-chunk (4 c per chunk)
    const int c0 = sG << 2;
    const float* gsrc = sv ? vg : kg;    // identical addressing for K and V loads

    // ---- prologue: Q [128t][64c] scaled+transposed+swizzled (512 thr, 1 pass) ----
    {
        const int cG = tid >> 5;         // 0..15
        const int ti = tid & 31;
        float4 q4[4];
        #pragma unroll
        for (int jj = 0; jj < 4; ++jj)
            q4[jj] = *(const float4*)(qg + (cG * 4 + jj) * 1024 + t0 + ti * 4);
        #pragma unroll
        for (int rr = 0; rr < 4; ++rr) {
            int trow = ti * 4 + rr;
            bf16_4 w;
            w[0] = (__bf16)(((const float*)&q4[0])[rr] * QSCALE);
            w[1] = (__bf16)(((const float*)&q4[1])[rr] * QSCALE);
            w[2] = (__bf16)(((const float*)&q4[2])[rr] * QSCALE);
            w[3] = (__bf16)(((const float*)&q4[3])[rr] * QSCALE);
            *(bf16_4*)&q_s[trow * STR + ((cG ^ (kap(trow) << 1)) << 2)] = w;
        }
    }
    // ---- K/V tile 0 (half the threads each) ----
    {
        float4 r4[4];
        #pragma unroll
        for (int jj = 0; jj < 4; ++jj)
            r4[jj] = *(const float4*)(gsrc + (c0 + jj) * 1024 + si * 4);
        if (!sv) write_k(k0, r4, si, sG);
        else     write_v(v0, r4, si, c0);
    }
    __syncthreads();

    // Q B-frags for this wave's 16-t tile (B[k=c][n=t]), in regs all loop
    bf16_8 qf[2];
    {
        int row = wave * 16 + i16;
        int x = kap(row);
        #pragma unroll
        for (int kk = 0; kk < 2; ++kk)
            qf[kk] = *(const bf16_8*)&q_s[row * STR + ((((kk << 2) | quad) ^ x) << 3)];
    }

    floatx4 O[4];
    #pragma unroll
    for (int cn = 0; cn < 4; ++cn) O[cn] = (floatx4){0.f, 0.f, 0.f, 0.f};
    float l = 0.f;

    bf16_8 afp[2];                       // af of tile is-1 (carried in regs)
    int vprev = 2, vcur = 0, vnext = 1;  // V buffer rotation (tile % 3)

    for (int is = 0; is < NSTEPS; ++is) {
        const __bf16* kc = (is & 1) ? k1 : k0;

        // global prefetch of tile is+1 (each thread: its K *or* V quarter-rows)
        float4 pr[4];
        if (is < NSTEPS - 1) {
            const int s0n = (is + 1) * 64;
            #pragma unroll
            for (int jj = 0; jj < 4; ++jj)
                pr[jj] = *(const float4*)(gsrc + (c0 + jj) * 1024 + s0n + si * 4);
        }

        // ---- S^T = K (Qs)^T ----
        floatx4 St[4];
        #pragma unroll
        for (int sb = 0; sb < 4; ++sb) {
            int srow = sb * 16 + i16;
            int x = (sb + (i16 >> 1)) & 7;            // kap(srow)
            bf16_8 kf0 = *(const bf16_8*)&kc[srow * STR + ((quad ^ x) << 3)];
            bf16_8 kf1 = *(const bf16_8*)&kc[srow * STR + (((4 | quad) ^ x) << 3)];
            floatx4 a = (floatx4){0.f, 0.f, 0.f, 0.f};
            a = __builtin_amdgcn_mfma_f32_16x16x32_bf16(kf0, qf[0], a, 0, 0, 0);
            a = __builtin_amdgcn_mfma_f32_16x16x32_bf16(kf1, qf[1], a, 0, 0, 0);
            St[sb] = a;
        }

        // ---- P = exp2(S^T), packed in-register ----
        unsigned c01[4], c23[4];
        #pragma unroll
        for (int sb = 0; sb < 4; ++sb) {
            float p0 = EXP2(St[sb][0]);
            float p1 = EXP2(St[sb][1]);
            float p2 = EXP2(St[sb][2]);
            float p3 = EXP2(St[sb][3]);
            l += (p0 + p1) + (p2 + p3);
            c01[sb] = pk_bf16(p0, p1);
            c23[sb] = pk_bf16(p2, p3);
        }
        // ---- C-layout -> B-frag via permlane swaps (no LDS) ----
        bf16_8 af[2];
        #pragma unroll
        for (int kk = 0; kk < 2; ++kk) {
            unsigned x0 = c01[2 * kk], y0 = c01[2 * kk + 1];
            unsigned x1 = c23[2 * kk], y1 = c23[2 * kk + 1];
            swap32(x0, y0); swap16(x0, y0);   // x0 = d0, y0 = d2
            swap32(x1, y1); swap16(x1, y1);   // x1 = d1, y1 = d3
            union { unsigned u[4]; bf16_8 v; } t;
            t.u[0] = x0; t.u[1] = x1; t.u[2] = y0; t.u[3] = y1;
            af[kk] = t.v;
        }

        // ---- PV_{is-1}: independent of QK_is/softmax_is -> fills latency ----
        if (is > 0) {
            const __bf16* vp = (vprev == 0) ? v0 : ((vprev == 1) ? v1 : v2);
            #pragma unroll
            for (int cn = 0; cn < 4; ++cn) {
                int crow = cn * 16 + i16;
                int xc = (cn + (i16 >> 1)) & 7;       // kap(crow)
                #pragma unroll
                for (int kk = 0; kk < 2; ++kk) {
                    bf16_8 vf = *(const bf16_8*)&vp[crow * STR + ((((kk << 2) | quad) ^ xc) << 3)];
                    O[cn] = __builtin_amdgcn_mfma_f32_16x16x32_bf16(vf, afp[kk], O[cn], 0, 0, 0);
                }
            }
        }
        afp[0] = af[0]; afp[1] = af[1];

        // ---- staging of tile is+1 (K -> (is+1)&1, V -> vnext) ----
        if (is < NSTEPS - 1) {
            if (!sv) {
                __bf16* kn = (is & 1) ? k0 : k1;
                write_k(kn, pr, si, sG);
            } else {
                __bf16* vn = (vnext == 0) ? v0 : ((vnext == 1) ? v1 : v2);
                write_v(vn, pr, si, c0);
            }
            __syncthreads();             // publish is+1, retire reads of K_is / V_{is-1}
        }
        // rotate V buffers
        vprev = vcur; vcur = vnext; vnext = (vnext == 2) ? 0 : vnext + 1;
    }

    // ---- final PV for tile 15 (in vprev after 16 rotations) ----
    {
        const __bf16* vp = (vprev == 0) ? v0 : ((vprev == 1) ? v1 : v2);
        #pragma unroll
        for (int cn = 0; cn < 4; ++cn) {
            int crow = cn * 16 + i16;
            int xc = (cn + (i16 >> 1)) & 7;
            #pragma unroll
            for (int kk = 0; kk < 2; ++kk) {
                bf16_8 vf = *(const bf16_8*)&vp[crow * STR + ((((kk << 2) | quad) ^ xc) << 3)];
                O[cn] = __builtin_amdgcn_mfma_f32_16x16x32_bf16(vf, afp[kk], O[cn], 0, 0, 0);
            }
        }
    }

    // ---- denominator (sum quads of column t) + direct O^T stores ----
    float s = l;
    s += __shfl_xor(s, 16);
    s += __shfl_xor(s, 32);
    const float linv = 1.0f / s;
    float* og = out + (size_t)bh * 65536 + t0 + wave * 16;
    #pragma unroll
    for (int cn = 0; cn < 4; ++cn)
        #pragma unroll
        for (int r = 0; r < 4; ++r)
            og[(cn * 16 + 4 * quad + r) * 1024 + i16] = O[cn][r] * linv;
}

extern "C" void kernel_launch(void* const* d_in, const int* in_sizes, int n_in,
                              void* d_out, int out_size, void* d_ws, size_t ws_size,
                              hipStream_t stream) {
    const float* qkv = (const float*)d_in[0];
    float* out = (float*)d_out;
    attn_kernel<<<dim3(512), dim3(NTHREADS), 0, stream>>>(qkv, out);
}